// Round 8
// baseline (63.524 us; speedup 1.0000x reference)
//
#include <hip/hip_runtime.h>
#include <stdint.h>
#include <stddef.h>

// Problem constants (fixed by the reference's setup_inputs):
//   attnQ [m=4, h=16, t=1024, d=64] f32, pe [257, 64] f32, s=128
//   out[m,h,i,j] = sum_d Q[m,h,i,d] * pe[clip(i-j,-128,128)+128, d]
//
// R8 insight: out row i = QP row i REVERSED with clamped-constant ends.
// Phase B writes QP[i][c] (f32) to LDS at dword d = 264 + (i&3) - c
// (reversed + per-row phase so reads are 16B-aligned), pads d<8+off = c256,
// d>264+off = c0. Phase C per thread per row: jc = clamp(j0, A-8, A+260),
// ONE conflict-free ds_read_b128, one nontemporal float4 store (~6 VALU
// vs R7's ~12 VALU + 3 conflicted LDS per 16B -- R7's Phase C VALU prep
// was co-limiting with the HBM store stream at ~60 us).
#define T_LEN 1024
#define D_DIM 64
#define BI    16            // query rows per tile (one MFMA M-tile)
#define NT    4             // i-tiles per block
#define QP_DW 276           // dwords per qp row plane (272 used; 276 = 4k,
                            // and 4-row plane stride ~ uniform 2-way banks)

typedef _Float16 h16;
typedef h16   h16x8 __attribute__((ext_vector_type(8)));
typedef float f32x4 __attribute__((ext_vector_type(4)));
typedef float vfloat4 __attribute__((ext_vector_type(4)));

__device__ __forceinline__ float4 ld4(const float* p) {
    return *reinterpret_cast<const float4*>(p);
}
__device__ __forceinline__ h16x8 cvt8h(float4 a, float4 b) {
    h16x8 r;
    r[0] = (h16)a.x; r[1] = (h16)a.y; r[2] = (h16)a.z; r[3] = (h16)a.w;
    r[4] = (h16)b.x; r[5] = (h16)b.y; r[6] = (h16)b.z; r[7] = (h16)b.w;
    return r;
}

#define SPLIT1(hi, lo, idx, val)                      \
    { const float _v = (val); const h16 _h = (h16)_v; \
      hi[idx] = _h; lo[idx] = (h16)(_v - (float)_h); }

__global__ __launch_bounds__(256, 4)
void relpos_fused(const float* __restrict__ Q,
                  const float* __restrict__ pe,
                  float* __restrict__ out) {
    __shared__ float qp_s[2][BI][QP_DW];   // 35328 B -> 4 blocks/CU

    const int tid   = threadIdx.x;
    const int mh    = blockIdx.x;          // 0..63  (m*h)
    const int by    = blockIdx.y;          // 0..15 -> i-tiles by*NT .. by*NT+3
    const int wave  = tid >> 6;
    const int lane  = tid & 63;
    const int row16 = lane & 15;           // MFMA free-dim index (M or N)
    const int kgrp  = lane >> 4;           // lane holds k = kk*32 + kgrp*8 + j

    // ---- persistent pe B-fragments (loaded once; f16) ----
    // B[k][col]: col = lane&15 -> pe row (cb + row16); k = kk*32 + kgrp*8 + j
#define PE_LOAD(N, B0, B1)                                                     \
    h16x8 B0, B1;                                                              \
    {                                                                          \
        const float* prow = pe + (size_t)(wave * 64 + (N) * 16 + row16) * D_DIM \
                               + kgrp * 8;                                     \
        B0 = cvt8h(ld4(prow),      ld4(prow + 4));                             \
        B1 = cvt8h(ld4(prow + 32), ld4(prow + 36));                            \
    }
    PE_LOAD(0, pb0_0, pb1_0)
    PE_LOAD(1, pb0_1, pb1_1)
    PE_LOAD(2, pb0_2, pb1_2)
    PE_LOAD(3, pb0_3, pb1_3)
    h16x8 pb0_t16, pb1_t16;        // pe row 256 broadcast to all lanes (wave 3)
    if (wave == 3) {
        const float* prow = pe + (size_t)256 * D_DIM + kgrp * 8;
        pb0_t16 = cvt8h(ld4(prow),      ld4(prow + 4));
        pb1_t16 = cvt8h(ld4(prow + 32), ld4(prow + 36));
    }

    float4 nqa, nqb, nqc, nqd;     // next tile's Q rows (issued early)
#define QLOAD(IT)                                                              \
    {                                                                          \
        const float* qrow = Q + ((size_t)mh * T_LEN + (IT) * BI + row16) * D_DIM \
                              + kgrp * 8;                                      \
        nqa = ld4(qrow);      nqb = ld4(qrow + 4);                             \
        nqc = ld4(qrow + 32); nqd = ld4(qrow + 36);                            \
    }

    // one col-tile: 4 MFMA + reversed f32 LDS writes.
    // D: QP row = kgrp*4 + j, QP col = cb + row16; dword d = 264 + j - col
    // (j == row&3 == the per-row phase shift).
#define TILE(N, B0, B1, BUF)                                                   \
    {                                                                          \
        f32x4 acc = {0.f, 0.f, 0.f, 0.f};                                      \
        acc = __builtin_amdgcn_mfma_f32_16x16x32_f16(a0h, B0, acc, 0, 0, 0);   \
        acc = __builtin_amdgcn_mfma_f32_16x16x32_f16(a1h, B1, acc, 0, 0, 0);   \
        acc = __builtin_amdgcn_mfma_f32_16x16x32_f16(a0l, B0, acc, 0, 0, 0);   \
        acc = __builtin_amdgcn_mfma_f32_16x16x32_f16(a1l, B1, acc, 0, 0, 0);   \
        const int col = wave * 64 + (N) * 16 + row16;                          \
        qp_s[BUF][kgrp * 4 + 0][264 + 0 - col] = acc[0];                       \
        qp_s[BUF][kgrp * 4 + 1][264 + 1 - col] = acc[1];                       \
        qp_s[BUF][kgrp * 4 + 2][264 + 2 - col] = acc[2];                       \
        qp_s[BUF][kgrp * 4 + 3][264 + 3 - col] = acc[3];                       \
        if ((N) == 0 && wave == 0 && row16 == 0) {   /* right pads: c0 */      \
            _Pragma("unroll")                                                  \
            for (int j = 0; j < 4; ++j)                                        \
                for (int d = 265 + j; d < 272; ++d)                            \
                    qp_s[BUF][kgrp * 4 + j][d] = acc[j];                       \
        }                                                                      \
    }

    // full B phase for the tile whose Q rows sit in nqa..nqd
#define BCOMPUTE(BUF)                                                          \
    {                                                                          \
        h16x8 a0h, a0l, a1h, a1l;                                             \
        SPLIT1(a0h, a0l, 0, nqa.x) SPLIT1(a0h, a0l, 1, nqa.y)                 \
        SPLIT1(a0h, a0l, 2, nqa.z) SPLIT1(a0h, a0l, 3, nqa.w)                 \
        SPLIT1(a0h, a0l, 4, nqb.x) SPLIT1(a0h, a0l, 5, nqb.y)                 \
        SPLIT1(a0h, a0l, 6, nqb.z) SPLIT1(a0h, a0l, 7, nqb.w)                 \
        SPLIT1(a1h, a1l, 0, nqc.x) SPLIT1(a1h, a1l, 1, nqc.y)                 \
        SPLIT1(a1h, a1l, 2, nqc.z) SPLIT1(a1h, a1l, 3, nqc.w)                 \
        SPLIT1(a1h, a1l, 4, nqd.x) SPLIT1(a1h, a1l, 5, nqd.y)                 \
        SPLIT1(a1h, a1l, 6, nqd.z) SPLIT1(a1h, a1l, 7, nqd.w)                 \
        TILE(0, pb0_0, pb1_0, BUF)                                             \
        TILE(1, pb0_1, pb1_1, BUF)                                             \
        TILE(2, pb0_2, pb1_2, BUF)                                             \
        TILE(3, pb0_3, pb1_3, BUF)                                             \
        if (wave == 3) {   /* col 256 tile: all D cols = c256 for its row */   \
            f32x4 acc = {0.f, 0.f, 0.f, 0.f};                                  \
            acc = __builtin_amdgcn_mfma_f32_16x16x32_f16(a0h, pb0_t16, acc, 0, 0, 0); \
            acc = __builtin_amdgcn_mfma_f32_16x16x32_f16(a1h, pb1_t16, acc, 0, 0, 0); \
            acc = __builtin_amdgcn_mfma_f32_16x16x32_f16(a0l, pb0_t16, acc, 0, 0, 0); \
            acc = __builtin_amdgcn_mfma_f32_16x16x32_f16(a1l, pb1_t16, acc, 0, 0, 0); \
            if (row16 == 0) {   /* real col256 at d=8+j, left pads d<8+j */    \
                _Pragma("unroll")                                              \
                for (int j = 0; j < 4; ++j) {                                  \
                    qp_s[BUF][kgrp * 4 + j][8 + j] = acc[j];                   \
                    for (int d = 0; d < 8 + j; ++d)                            \
                        qp_s[BUF][kgrp * 4 + j][d] = acc[j];                   \
                }                                                              \
            }                                                                  \
        }                                                                      \
    }

    // ---------------- prologue: tile 0 into buffer 0 ----------------
    QLOAD(by * NT)
    BCOMPUTE(0)

    const int j0 = tid << 2;
#pragma unroll
    for (int t = 0; t < NT; ++t) {
        __syncthreads();                       // buf[t&1] ready; other free
        if (t + 1 < NT) { QLOAD(by * NT + t + 1) }

        // ---- Phase C: reversed-window read + streaming store ----
        // dword d holds col 264+(r&3)-d; read at d = jc-A+8 gives
        // col = i-j+128 (interior) or pad constants (clamped). A = aligned
        // window base; jc = clamp(j0, A-8, A+260); all reads 16B-aligned,
        // consecutive lanes -> consecutive 16B (conflict-free b128).
        {
            const int it  = by * NT + t;
            const int i0t = it * BI;
            float* dstf = out + ((size_t)mh * T_LEN + i0t) * T_LEN + j0;
            const float* qb = &qp_s[t & 1][0][0];
#pragma unroll 4
            for (int r = 0; r < BI; ++r) {
                const int i  = i0t + r;
                const int A  = i - 128 - (r & 3);        // == 0 (mod 4)
                int jc = j0 < A - 8 ? A - 8 : j0;
                jc = jc > A + 260 ? A + 260 : jc;
                const float* src = qb + r * QP_DW + (jc - A + 8);
                const vfloat4 v = *reinterpret_cast<const vfloat4*>(src);
                __builtin_nontemporal_store(v, reinterpret_cast<vfloat4*>(dstf));
                dstf += T_LEN;
            }
        }

        if (t + 1 < NT) { BCOMPUTE((t + 1) & 1) }
    }
}

extern "C" void kernel_launch(void* const* d_in, const int* in_sizes, int n_in,
                              void* d_out, int out_size, void* d_ws, size_t ws_size,
                              hipStream_t stream) {
    const float* Q  = (const float*)d_in[0];
    // d_in[1] = attnK (only its shape matters; t2 == T_LEN)
    const float* pe = (const float*)d_in[2];
    float* out = (float*)d_out;

    const int mh = in_sizes[0] / (T_LEN * D_DIM);   // m*h = 64
    dim3 grid(mh, (T_LEN / BI) / NT);                // (64, 16) = 1024 blocks
    relpos_fused<<<grid, 256, 0, stream>>>(Q, pe, out);
}

// Round 9
// 59.753 us; speedup vs baseline: 1.0631x; 1.0631x over previous
//
#include <hip/hip_runtime.h>
#include <stdint.h>
#include <stddef.h>

// Problem constants (fixed by the reference's setup_inputs):
//   attnQ [m=4, h=16, t=1024, d=64] f32, pe [257, 64] f32, s=128
//   out[m,h,i,j] = sum_d Q[m,h,i,d] * pe[clip(i-j,-128,128)+128, d]
//
// R9 = R8 reversed-window layout + two fixes for store-stream continuity:
//   1. Raw s_barrier with lgkmcnt(0) ONLY (no vmcnt drain): __syncthreads'
//      implicit s_waitcnt vmcnt(0) drained the 64 KB store burst at every
//      tile boundary (the m97 barrier-drain stall) -- global stores have no
//      LDS hazard, so they now stay in flight across the whole kernel.
//   2. Plain float4 stores (R8's nontemporal store was a suspected
//      regression vs the 6.6 TB/s fill kernels' plain stores).
// Layout: Phase B writes QP[i][c] (f32) at dword d = 264+(i&3)-c (reversed,
// per-row phase-aligned); pads: d<8+(i&3) = c256, d>264+(i&3) = c0. Phase C:
// jc = clamp(j0, A-8, A+260), one conflict-free ds_read_b128, one store.
#define T_LEN 1024
#define D_DIM 64
#define BI    16            // query rows per tile (one MFMA M-tile)
#define NT    4             // i-tiles per block
#define QP_DW 276           // dwords per qp row plane

typedef _Float16 h16;
typedef h16   h16x8 __attribute__((ext_vector_type(8)));
typedef float f32x4 __attribute__((ext_vector_type(4)));
typedef float vfloat4 __attribute__((ext_vector_type(4)));

__device__ __forceinline__ float4 ld4(const float* p) {
    return *reinterpret_cast<const float4*>(p);
}
__device__ __forceinline__ h16x8 cvt8h(float4 a, float4 b) {
    h16x8 r;
    r[0] = (h16)a.x; r[1] = (h16)a.y; r[2] = (h16)a.z; r[3] = (h16)a.w;
    r[4] = (h16)b.x; r[5] = (h16)b.y; r[6] = (h16)b.z; r[7] = (h16)b.w;
    return r;
}

#define SPLIT1(hi, lo, idx, val)                      \
    { const float _v = (val); const h16 _h = (h16)_v; \
      hi[idx] = _h; lo[idx] = (h16)(_v - (float)_h); }

// Barrier with LDS-only wait: global stores/loads stay in flight.
// "memory" clobber pins all memory ops; sched_barrier(0) pins scheduling
// (rule #18: hipcc can hoist reg-only ops past inline-asm waitcnt).
#define TILEBAR()                                               \
    do {                                                        \
        asm volatile("s_waitcnt lgkmcnt(0)" ::: "memory");      \
        __builtin_amdgcn_s_barrier();                           \
        __builtin_amdgcn_sched_barrier(0);                      \
    } while (0)

__global__ __launch_bounds__(256, 4)
void relpos_fused(const float* __restrict__ Q,
                  const float* __restrict__ pe,
                  float* __restrict__ out) {
    __shared__ float qp_s[2][BI][QP_DW];   // 35328 B -> 4 blocks/CU

    const int tid   = threadIdx.x;
    const int mh    = blockIdx.x;          // 0..63  (m*h)
    const int by    = blockIdx.y;          // 0..15 -> i-tiles by*NT .. by*NT+3
    const int wave  = tid >> 6;
    const int lane  = tid & 63;
    const int row16 = lane & 15;           // MFMA free-dim index (M or N)
    const int kgrp  = lane >> 4;           // lane holds k = kk*32 + kgrp*8 + j

    // ---- persistent pe B-fragments (loaded once; f16) ----
    // B[k][col]: col = lane&15 -> pe row (cb + row16); k = kk*32 + kgrp*8 + j
#define PE_LOAD(N, B0, B1)                                                     \
    h16x8 B0, B1;                                                              \
    {                                                                          \
        const float* prow = pe + (size_t)(wave * 64 + (N) * 16 + row16) * D_DIM \
                               + kgrp * 8;                                     \
        B0 = cvt8h(ld4(prow),      ld4(prow + 4));                             \
        B1 = cvt8h(ld4(prow + 32), ld4(prow + 36));                            \
    }
    PE_LOAD(0, pb0_0, pb1_0)
    PE_LOAD(1, pb0_1, pb1_1)
    PE_LOAD(2, pb0_2, pb1_2)
    PE_LOAD(3, pb0_3, pb1_3)
    h16x8 pb0_t16, pb1_t16;        // pe row 256 broadcast to all lanes (wave 3)
    if (wave == 3) {
        const float* prow = pe + (size_t)256 * D_DIM + kgrp * 8;
        pb0_t16 = cvt8h(ld4(prow),      ld4(prow + 4));
        pb1_t16 = cvt8h(ld4(prow + 32), ld4(prow + 36));
    }

    float4 nqa, nqb, nqc, nqd;     // next tile's Q rows (issued early)
#define QLOAD(IT)                                                              \
    {                                                                          \
        const float* qrow = Q + ((size_t)mh * T_LEN + (IT) * BI + row16) * D_DIM \
                              + kgrp * 8;                                      \
        nqa = ld4(qrow);      nqb = ld4(qrow + 4);                             \
        nqc = ld4(qrow + 32); nqd = ld4(qrow + 36);                            \
    }

    // one col-tile: 4 MFMA + reversed f32 LDS writes.
    // D: QP row = kgrp*4 + j, QP col = cb + row16; dword d = 264 + j - col.
#define TILE(N, B0, B1, BUF)                                                   \
    {                                                                          \
        f32x4 acc = {0.f, 0.f, 0.f, 0.f};                                      \
        acc = __builtin_amdgcn_mfma_f32_16x16x32_f16(a0h, B0, acc, 0, 0, 0);   \
        acc = __builtin_amdgcn_mfma_f32_16x16x32_f16(a1h, B1, acc, 0, 0, 0);   \
        acc = __builtin_amdgcn_mfma_f32_16x16x32_f16(a0l, B0, acc, 0, 0, 0);   \
        acc = __builtin_amdgcn_mfma_f32_16x16x32_f16(a1l, B1, acc, 0, 0, 0);   \
        const int col = wave * 64 + (N) * 16 + row16;                          \
        qp_s[BUF][kgrp * 4 + 0][264 + 0 - col] = acc[0];                       \
        qp_s[BUF][kgrp * 4 + 1][264 + 1 - col] = acc[1];                       \
        qp_s[BUF][kgrp * 4 + 2][264 + 2 - col] = acc[2];                       \
        qp_s[BUF][kgrp * 4 + 3][264 + 3 - col] = acc[3];                       \
        if ((N) == 0 && wave == 0 && row16 == 0) {   /* right pads: c0 */      \
            _Pragma("unroll")                                                  \
            for (int j = 0; j < 4; ++j)                                        \
                for (int d = 265 + j; d < 272; ++d)                            \
                    qp_s[BUF][kgrp * 4 + j][d] = acc[j];                       \
        }                                                                      \
    }

    // full B phase for the tile whose Q rows sit in nqa..nqd
#define BCOMPUTE(BUF)                                                          \
    {                                                                          \
        h16x8 a0h, a0l, a1h, a1l;                                             \
        SPLIT1(a0h, a0l, 0, nqa.x) SPLIT1(a0h, a0l, 1, nqa.y)                 \
        SPLIT1(a0h, a0l, 2, nqa.z) SPLIT1(a0h, a0l, 3, nqa.w)                 \
        SPLIT1(a0h, a0l, 4, nqb.x) SPLIT1(a0h, a0l, 5, nqb.y)                 \
        SPLIT1(a0h, a0l, 6, nqb.z) SPLIT1(a0h, a0l, 7, nqb.w)                 \
        SPLIT1(a1h, a1l, 0, nqc.x) SPLIT1(a1h, a1l, 1, nqc.y)                 \
        SPLIT1(a1h, a1l, 2, nqc.z) SPLIT1(a1h, a1l, 3, nqc.w)                 \
        SPLIT1(a1h, a1l, 4, nqd.x) SPLIT1(a1h, a1l, 5, nqd.y)                 \
        SPLIT1(a1h, a1l, 6, nqd.z) SPLIT1(a1h, a1l, 7, nqd.w)                 \
        TILE(0, pb0_0, pb1_0, BUF)                                             \
        TILE(1, pb0_1, pb1_1, BUF)                                             \
        TILE(2, pb0_2, pb1_2, BUF)                                             \
        TILE(3, pb0_3, pb1_3, BUF)                                             \
        if (wave == 3) {   /* col 256 tile */                                  \
            f32x4 acc = {0.f, 0.f, 0.f, 0.f};                                  \
            acc = __builtin_amdgcn_mfma_f32_16x16x32_f16(a0h, pb0_t16, acc, 0, 0, 0); \
            acc = __builtin_amdgcn_mfma_f32_16x16x32_f16(a1h, pb1_t16, acc, 0, 0, 0); \
            acc = __builtin_amdgcn_mfma_f32_16x16x32_f16(a0l, pb0_t16, acc, 0, 0, 0); \
            acc = __builtin_amdgcn_mfma_f32_16x16x32_f16(a1l, pb1_t16, acc, 0, 0, 0); \
            if (row16 == 0) {   /* real col256 at d=8+j, left pads d<8+j */    \
                _Pragma("unroll")                                              \
                for (int j = 0; j < 4; ++j) {                                  \
                    qp_s[BUF][kgrp * 4 + j][8 + j] = acc[j];                   \
                    for (int d = 0; d < 8 + j; ++d)                            \
                        qp_s[BUF][kgrp * 4 + j][d] = acc[j];                   \
                }                                                              \
            }                                                                  \
        }                                                                      \
    }

    // ---------------- prologue: tile 0 into buffer 0 ----------------
    QLOAD(by * NT)
    BCOMPUTE(0)

    const int j0 = tid << 2;
#pragma unroll
    for (int t = 0; t < NT; ++t) {
        TILEBAR();                             // LDS-only wait; stores stay in flight
        if (t + 1 < NT) { QLOAD(by * NT + t + 1) }

        // ---- Phase C: reversed-window read + coalesced store ----
        // dword d holds col 264+(r&3)-d; read at d = jc-A+8 gives
        // col = i-j+128 (interior) or pad constants (clamped).
        {
            const int it  = by * NT + t;
            const int i0t = it * BI;
            float* dstf = out + ((size_t)mh * T_LEN + i0t) * T_LEN + j0;
            const float* qb = &qp_s[t & 1][0][0];
#pragma unroll 4
            for (int r = 0; r < BI; ++r) {
                const int i  = i0t + r;
                const int A  = i - 128 - (r & 3);        // == 0 (mod 4)
                int jc = j0 < A - 8 ? A - 8 : j0;
                jc = jc > A + 260 ? A + 260 : jc;
                const float* src = qb + r * QP_DW + (jc - A + 8);
                const vfloat4 v = *reinterpret_cast<const vfloat4*>(src);
                *reinterpret_cast<vfloat4*>(dstf) = v;
                dstf += T_LEN;
            }
        }

        if (t + 1 < NT) { BCOMPUTE((t + 1) & 1) }
    }
}

extern "C" void kernel_launch(void* const* d_in, const int* in_sizes, int n_in,
                              void* d_out, int out_size, void* d_ws, size_t ws_size,
                              hipStream_t stream) {
    const float* Q  = (const float*)d_in[0];
    // d_in[1] = attnK (only its shape matters; t2 == T_LEN)
    const float* pe = (const float*)d_in[2];
    float* out = (float*)d_out;

    const int mh = in_sizes[0] / (T_LEN * D_DIM);   // m*h = 64
    dim3 grid(mh, (T_LEN / BI) / NT);                // (64, 16) = 1024 blocks
    relpos_fused<<<grid, 256, 0, stream>>>(Q, pe, out);
}